// Round 9
// baseline (293.779 us; speedup 1.0000x reference)
//
#include <hip/hip_runtime.h>
#include <hip/hip_bf16.h>
#include <math.h>

typedef short bf16x8 __attribute__((ext_vector_type(8)));
typedef float f32x4 __attribute__((ext_vector_type(4)));

#define BSHIFT 7
#define BWIDTH 128      // nodes per bucket
#define PCHUNK 4096     // edges per partition block

// ---------------------------------------------------------------------------
// prep: zero bucket counters (block 0) + bf16-transpose both weights
// ---------------------------------------------------------------------------
__global__ void prep_kernel(int* __restrict__ bcnt,
                            const float* __restrict__ W1, const float* __restrict__ W2,
                            __hip_bfloat16* __restrict__ W1t,
                            __hip_bfloat16* __restrict__ W2t) {
    if (blockIdx.x == 0) {
        bcnt[threadIdx.x] = 0;
        bcnt[threadIdx.x + 256] = 0;
        return;
    }
    int idx = (blockIdx.x - 1) * 256 + threadIdx.x;
    const int n1 = 128 * 256;
    if (idx < n1) {
        int nn = idx >> 8, kk = idx & 255;
        W1t[idx] = __float2bfloat16(W1[kk * 128 + nn]);
    } else {
        int j = idx - n1;
        if (j < 64 * 128) {
            int nn = j >> 7, kk = j & 127;
            W2t[j] = __float2bfloat16(W2[kk * 64 + nn]);
        }
    }
}

// ---------------------------------------------------------------------------
// Bucketed CSR build; tmp packed: (src << 7) | dst_local
// ---------------------------------------------------------------------------
__global__ __launch_bounds__(256) void bucket_hist(const int* __restrict__ ei, int E,
                                                   int* __restrict__ bcnt) {
    __shared__ int h[512];
    int tid = threadIdx.x;
    for (int i = tid; i < 512; i += 256) h[i] = 0;
    __syncthreads();
    int start = blockIdx.x * PCHUNK;
    int cnt = min(PCHUNK, E - start);
    for (int i = tid; i < cnt; i += 256)
        atomicAdd(&h[ei[E + start + i] >> BSHIFT], 1);
    __syncthreads();
    for (int i = tid; i < 512; i += 256)
        if (h[i]) atomicAdd(&bcnt[i], h[i]);
}

__global__ __launch_bounds__(512) void bucket_scan(const int* __restrict__ bcnt,
                                                   int* __restrict__ bbase,
                                                   int* __restrict__ bcur,
                                                   int nbk, int n) {
    __shared__ int s[512];
    int tid = threadIdx.x;
    int nodes = 0;
    if (tid < nbk) nodes = min(BWIDTH, n - (tid << BSHIFT));
    int v = (tid < nbk) ? bcnt[tid] + nodes : 0;
    s[tid] = v;
    __syncthreads();
    #pragma unroll
    for (int o = 1; o < 512; o <<= 1) {
        int t = (tid >= o) ? s[tid - o] : 0;
        __syncthreads();
        s[tid] += t;
        __syncthreads();
    }
    if (tid < nbk) {
        int ex = s[tid] - v;
        bbase[tid] = ex;
        bcur[tid] = ex - (tid << BSHIFT);
    }
    if (tid == nbk) bbase[nbk] = s[tid];
}

__global__ __launch_bounds__(256) void partition_edges(const int* __restrict__ ei, int E,
                                                       int* __restrict__ bcur,
                                                       int* __restrict__ tmp) {
    __shared__ int2 stage[PCHUNK];
    __shared__ int h[512];
    __shared__ int lbase[512];
    int tid = threadIdx.x;
    int start = blockIdx.x * PCHUNK;
    int cnt = min(PCHUNK, E - start);
    for (int i = tid; i < 512; i += 256) h[i] = 0;
    __syncthreads();
    for (int i = tid; i < cnt; i += 256) {
        int s = ei[start + i];
        int d = ei[E + start + i];
        stage[i] = make_int2(s, d);
        atomicAdd(&h[d >> BSHIFT], 1);
    }
    __syncthreads();
    for (int i = tid; i < 512; i += 256) {
        if (h[i] > 0) lbase[i] = atomicAdd(&bcur[i], h[i]);
        h[i] = 0;
    }
    __syncthreads();
    for (int i = tid; i < cnt; i += 256) {
        int2 e = stage[i];
        int b = e.y >> BSHIFT;
        int r = atomicAdd(&h[b], 1);
        tmp[lbase[b] + r] = (e.x << BSHIFT) | (e.y & (BWIDTH - 1));
    }
}

__device__ __forceinline__ float leaky(float r) {
    return r < 0.f ? 0.2f * r : r;
}

// ---------------------------------------------------------------------------
// bucket_csr + FUSED layer-1 edge-record emission.
// rec1[slot] = { src*256 (byte off into h1), w0_f32_bits, w1_f32_bits, dst }.
// Weights computed ONCE here (f32-exact) instead of per-channel-group in agg.
// Requires a_s1/a_d1 (gemm1 runs before this kernel).
// ---------------------------------------------------------------------------
__global__ __launch_bounds__(256) void bucket_csr(const int* __restrict__ bbase,
                                                  const int* __restrict__ tmp,
                                                  int* __restrict__ offs,
                                                  uint4* __restrict__ rec1,
                                                  const float* __restrict__ asv1,
                                                  const float* __restrict__ adv1,
                                                  int n, int nbk) {
    __shared__ int cnt[BWIDTH];
    __shared__ int sa[BWIDTH];
    __shared__ int cur[BWIDTH];
    __shared__ float adl[2 * BWIDTH];
    int b = blockIdx.x;
    int tid = threadIdx.x;
    int node0 = b << BSHIFT;
    int nnodes = min(BWIDTH, n - node0);
    int cb = bbase[b];
    int ce = bbase[b + 1];
    int tb = cb - node0;
    int ecnt = (ce - cb) - nnodes;

    if (tid < BWIDTH) cnt[tid] = (tid < nnodes) ? 1 : 0;
    if (tid < 2 * nnodes) adl[tid] = adv1[2 * node0 + tid];
    __syncthreads();
    for (int i = tid; i < ecnt; i += 256)
        atomicAdd(&cnt[tmp[tb + i] & (BWIDTH - 1)], 1);
    __syncthreads();
    if (tid < BWIDTH) sa[tid] = cnt[tid];
    __syncthreads();
    #pragma unroll
    for (int o = 1; o < BWIDTH; o <<= 1) {
        int v = 0;
        if (tid < BWIDTH) { v = sa[tid]; if (tid >= o) v += sa[tid - o]; }
        __syncthreads();
        if (tid < BWIDTH) sa[tid] = v;
        __syncthreads();
    }
    if (tid < BWIDTH) {
        int ex = sa[tid] - cnt[tid];
        if (tid < nnodes) {
            int dst = node0 + tid;
            offs[dst] = cb + ex;
            float2 a = *(const float2*)(asv1 + 2 * dst);
            float w0 = __expf(leaky(a.x + adl[2 * tid]));
            float w1 = __expf(leaky(a.y + adl[2 * tid + 1]));
            rec1[cb + ex] = make_uint4((unsigned)dst * 256u,
                                       __float_as_uint(w0), __float_as_uint(w1),
                                       (unsigned)dst);
        }
        cur[tid] = ex + (tid < nnodes ? 1 : 0);
    }
    if (b == nbk - 1 && tid == 0) offs[n] = ce;
    __syncthreads();
    for (int i = tid; i < ecnt; i += 256) {
        int e = tmp[tb + i];
        int li = e & (BWIDTH - 1);
        int r = atomicAdd(&cur[li], 1);
        int src = e >> BSHIFT;
        int dst = node0 + li;
        float2 a = *(const float2*)(asv1 + 2 * src);
        float w0 = __expf(leaky(a.x + adl[2 * li]));
        float w1 = __expf(leaky(a.y + adl[2 * li + 1]));
        rec1[cb + r] = make_uint4((unsigned)src * 256u,
                                  __float_as_uint(w0), __float_as_uint(w1),
                                  (unsigned)dst);
    }
}

// ---------------------------------------------------------------------------
// Layer-2 edge records from rec1: rec2 = { src*128 (byte off), w_f32_bits }.
// ---------------------------------------------------------------------------
__global__ __launch_bounds__(256) void build_rec2(
    const uint4* __restrict__ rec1, const float* __restrict__ asv2,
    const float* __restrict__ adv2, uint2* __restrict__ rec2, int tot) {
    int i = blockIdx.x * blockDim.x + threadIdx.x;
    if (i >= tot) return;
    uint4 r = rec1[i];
    int src = (int)(r.x >> 8);
    int dst = (int)r.w;
    float w = __expf(leaky(asv2[src] + adv2[dst]));
    rec2[i] = make_uint2(r.x >> 1, __float_as_uint(w));
}

// ---------------------------------------------------------------------------
// MFMA bf16 GEMM + fused attention dots. B-panel staged in LDS (the REUSED
// operand) in 128-k-column chunks; row pad +8 elems. A streamed per-lane from
// global, chunk loads issued BEFORE the B-stage barrier.
// ---------------------------------------------------------------------------
template <bool A_BF16, int NT, int HEADS, int KSTEPS>
__global__ __launch_bounds__(256) void gemm_att(
    const void* __restrict__ Av, const __hip_bfloat16* __restrict__ Bt,
    __hip_bfloat16* __restrict__ C,
    const float* __restrict__ atts, const float* __restrict__ attd,
    float* __restrict__ a_s, float* __restrict__ a_d, int M) {
    constexpr int K = KSTEPS * 32;
    constexpr int N = NT * 16;
    constexpr int KH = 128;
    constexpr int NCH = (K + KH - 1) / KH;
    constexpr int LDB = KH + 8;
    __shared__ __hip_bfloat16 Bs[N][LDB];

    int tid = threadIdx.x;
    int w = tid >> 6, l = tid & 63;
    int q = l >> 4, m16 = l & 15;
    int bm = blockIdx.x * 64;
    int arow = bm + w * 16 + m16;
    if (arow >= M) arow = M - 1;

    f32x4 acc[NT];
    #pragma unroll
    for (int t = 0; t < NT; t++) acc[t] = (f32x4){0.f, 0.f, 0.f, 0.f};

    #pragma unroll
    for (int ch = 0; ch < NCH; ch++) {
        const int cb = ch * KH;
        bf16x8 af[4];
        float4 st[8];
        if (A_BF16) {
            const __hip_bfloat16* A = (const __hip_bfloat16*)Av + (size_t)arow * K + cb + q * 8;
            #pragma unroll
            for (int t = 0; t < 4; t++)
                af[t] = *(const bf16x8*)(A + t * 32);
        } else {
            const float* A = (const float*)Av + (size_t)arow * K + cb + q * 8;
            #pragma unroll
            for (int t = 0; t < 4; t++) {
                st[2 * t]     = *(const float4*)(A + t * 32);
                st[2 * t + 1] = *(const float4*)(A + t * 32 + 4);
            }
        }
        for (int i = tid; i < (N * KH) / 8; i += 256) {
            int row = i >> 4;
            int k = (i & 15) * 8;
            *(uint4*)&Bs[row][k] = *(const uint4*)(Bt + (size_t)row * K + cb + k);
        }
        __syncthreads();
        if (!A_BF16) {
            #pragma unroll
            for (int t = 0; t < 4; t++) {
                union { __hip_bfloat16 h[8]; bf16x8 v; } u;
                float4 v0 = st[2 * t], v1 = st[2 * t + 1];
                u.h[0] = __float2bfloat16(v0.x); u.h[1] = __float2bfloat16(v0.y);
                u.h[2] = __float2bfloat16(v0.z); u.h[3] = __float2bfloat16(v0.w);
                u.h[4] = __float2bfloat16(v1.x); u.h[5] = __float2bfloat16(v1.y);
                u.h[6] = __float2bfloat16(v1.z); u.h[7] = __float2bfloat16(v1.w);
                af[t] = u.v;
            }
        }
        #pragma unroll
        for (int t = 0; t < 4; t++) {
            #pragma unroll
            for (int c = 0; c < NT; c++) {
                bf16x8 b = *(const bf16x8*)&Bs[c * 16 + m16][t * 32 + q * 8];
                acc[c] = __builtin_amdgcn_mfma_f32_16x16x32_bf16(af[t], b, acc[c], 0, 0, 0);
            }
        }
        if (ch + 1 < NCH) __syncthreads();
    }

    #pragma unroll
    for (int t = 0; t < NT; t++) {
        #pragma unroll
        for (int r = 0; r < 4; r++) {
            int row = bm + w * 16 + q * 4 + r;
            if (row < M) C[(size_t)row * N + t * 16 + m16] = __float2bfloat16(acc[t][r]);
        }
    }

    float ps[HEADS][4], pd[HEADS][4];
    #pragma unroll
    for (int hh = 0; hh < HEADS; hh++)
        #pragma unroll
        for (int r = 0; r < 4; r++) { ps[hh][r] = 0.f; pd[hh][r] = 0.f; }
    #pragma unroll
    for (int t = 0; t < NT; t++) {
        int ch = t * 16 + m16;
        float asw = atts[ch], adw = attd[ch];
        int hh = (HEADS == 2) ? (t >> 2) : 0;
        #pragma unroll
        for (int r = 0; r < 4; r++) {
            ps[hh][r] = fmaf(acc[t][r], asw, ps[hh][r]);
            pd[hh][r] = fmaf(acc[t][r], adw, pd[hh][r]);
        }
    }
    #pragma unroll
    for (int o = 1; o < 16; o <<= 1) {
        #pragma unroll
        for (int hh = 0; hh < HEADS; hh++)
            #pragma unroll
            for (int r = 0; r < 4; r++) {
                ps[hh][r] += __shfl_xor(ps[hh][r], o);
                pd[hh][r] += __shfl_xor(pd[hh][r], o);
            }
    }
    if (m16 == 0) {
        #pragma unroll
        for (int r = 0; r < 4; r++) {
            int row = bm + w * 16 + q * 4 + r;
            if (row < M) {
                if (HEADS == 2) {
                    a_s[row * 2]     = ps[0][r];
                    a_s[row * 2 + 1] = ps[1][r];
                    a_d[row * 2]     = pd[0][r];
                    a_d[row * 2 + 1] = pd[1][r];
                } else {
                    a_s[row] = ps[0][r];
                    a_d[row] = pd[0][r];
                }
            }
        }
    }
}

__device__ __forceinline__ void unpack2(unsigned u, float& lo, float& hi) {
    lo = __uint_as_float(u << 16);
    hi = __uint_as_float(u & 0xffff0000u);
}

// ---------------------------------------------------------------------------
// Edge softmax + aggregation, layer 1 (heads=2), RECORD-DRIVEN.
// Per 4-edge step: 4 broadcast rec1 loads + 4 row gathers (32-bit voffset)
// + unpack/FMA. No exp, no asv gather, no srcs, no 64-bit address mul.
// ---------------------------------------------------------------------------
__global__ __launch_bounds__(256) void edge_agg_l1(
    const int* __restrict__ offs, const uint4* __restrict__ rec1,
    const __hip_bfloat16* __restrict__ h1, const float* __restrict__ bias,
    __hip_bfloat16* __restrict__ out, int n) {
    int d = (blockIdx.x * blockDim.x + threadIdx.x) >> 6;
    int lane = threadIdx.x & 63;
    if (d >= n) return;
    int start = offs[d], end = offs[d + 1];
    int cnt = end - start;
    int sub = lane & 15;        // channel segment (8 ch)
    int g = lane >> 4;          // edge subgroup 0..3
    unsigned cboff = (unsigned)(sub * 8) * 2u;   // byte offset of lane's channels
    int hsel = sub >> 3;
    const char* hb = (const char*)h1;

    float wsum = 0.f;
    float acc[8];
    #pragma unroll
    for (int k = 0; k < 8; k++) acc[k] = 0.f;

    int full = cnt >> 2;
    int ib = start + g;
    int jj = 0;
    uint4 pA, pB, pC, pD;
    if (jj + 4 <= full) {
        pA = rec1[ib];      pB = rec1[ib + 4];
        pC = rec1[ib + 8];  pD = rec1[ib + 12];
    }
    for (; jj + 4 <= full; jj += 4) {
        uint4 rA = pA, rB = pB, rC = pC, rD = pD;
        if (jj + 8 <= full) {
            int nb = ib + (jj + 4) * 4;
            pA = rec1[nb];      pB = rec1[nb + 4];
            pC = rec1[nb + 8];  pD = rec1[nb + 12];
        }
        uint4 vA = *(const uint4*)(hb + (rA.x + cboff));
        uint4 vB = *(const uint4*)(hb + (rB.x + cboff));
        uint4 vC = *(const uint4*)(hb + (rC.x + cboff));
        uint4 vD = *(const uint4*)(hb + (rD.x + cboff));
        float wA = __uint_as_float(hsel ? rA.z : rA.y);
        float wB = __uint_as_float(hsel ? rB.z : rB.y);
        float wC = __uint_as_float(hsel ? rC.z : rC.y);
        float wD = __uint_as_float(hsel ? rD.z : rD.y);
        wsum += (wA + wB) + (wC + wD);
        float f0, f1, f2, f3, f4, f5, f6, f7;
        unpack2(vA.x, f0, f1); unpack2(vA.y, f2, f3);
        unpack2(vA.z, f4, f5); unpack2(vA.w, f6, f7);
        acc[0] = fmaf(wA, f0, acc[0]); acc[1] = fmaf(wA, f1, acc[1]);
        acc[2] = fmaf(wA, f2, acc[2]); acc[3] = fmaf(wA, f3, acc[3]);
        acc[4] = fmaf(wA, f4, acc[4]); acc[5] = fmaf(wA, f5, acc[5]);
        acc[6] = fmaf(wA, f6, acc[6]); acc[7] = fmaf(wA, f7, acc[7]);
        unpack2(vB.x, f0, f1); unpack2(vB.y, f2, f3);
        unpack2(vB.z, f4, f5); unpack2(vB.w, f6, f7);
        acc[0] = fmaf(wB, f0, acc[0]); acc[1] = fmaf(wB, f1, acc[1]);
        acc[2] = fmaf(wB, f2, acc[2]); acc[3] = fmaf(wB, f3, acc[3]);
        acc[4] = fmaf(wB, f4, acc[4]); acc[5] = fmaf(wB, f5, acc[5]);
        acc[6] = fmaf(wB, f6, acc[6]); acc[7] = fmaf(wB, f7, acc[7]);
        unpack2(vC.x, f0, f1); unpack2(vC.y, f2, f3);
        unpack2(vC.z, f4, f5); unpack2(vC.w, f6, f7);
        acc[0] = fmaf(wC, f0, acc[0]); acc[1] = fmaf(wC, f1, acc[1]);
        acc[2] = fmaf(wC, f2, acc[2]); acc[3] = fmaf(wC, f3, acc[3]);
        acc[4] = fmaf(wC, f4, acc[4]); acc[5] = fmaf(wC, f5, acc[5]);
        acc[6] = fmaf(wC, f6, acc[6]); acc[7] = fmaf(wC, f7, acc[7]);
        unpack2(vD.x, f0, f1); unpack2(vD.y, f2, f3);
        unpack2(vD.z, f4, f5); unpack2(vD.w, f6, f7);
        acc[0] = fmaf(wD, f0, acc[0]); acc[1] = fmaf(wD, f1, acc[1]);
        acc[2] = fmaf(wD, f2, acc[2]); acc[3] = fmaf(wD, f3, acc[3]);
        acc[4] = fmaf(wD, f4, acc[4]); acc[5] = fmaf(wD, f5, acc[5]);
        acc[6] = fmaf(wD, f6, acc[6]); acc[7] = fmaf(wD, f7, acc[7]);
    }
    for (; jj < full; jj++) {
        uint4 r = rec1[ib + jj * 4];
        uint4 v = *(const uint4*)(hb + (r.x + cboff));
        float wA = __uint_as_float(hsel ? r.z : r.y);
        wsum += wA;
        float f0, f1, f2, f3, f4, f5, f6, f7;
        unpack2(v.x, f0, f1); unpack2(v.y, f2, f3);
        unpack2(v.z, f4, f5); unpack2(v.w, f6, f7);
        acc[0] = fmaf(wA, f0, acc[0]); acc[1] = fmaf(wA, f1, acc[1]);
        acc[2] = fmaf(wA, f2, acc[2]); acc[3] = fmaf(wA, f3, acc[3]);
        acc[4] = fmaf(wA, f4, acc[4]); acc[5] = fmaf(wA, f5, acc[5]);
        acc[6] = fmaf(wA, f6, acc[6]); acc[7] = fmaf(wA, f7, acc[7]);
    }
    if (full * 4 + g < cnt) {
        uint4 r = rec1[ib + full * 4];
        uint4 v = *(const uint4*)(hb + (r.x + cboff));
        float wA = __uint_as_float(hsel ? r.z : r.y);
        wsum += wA;
        float f0, f1, f2, f3, f4, f5, f6, f7;
        unpack2(v.x, f0, f1); unpack2(v.y, f2, f3);
        unpack2(v.z, f4, f5); unpack2(v.w, f6, f7);
        acc[0] = fmaf(wA, f0, acc[0]); acc[1] = fmaf(wA, f1, acc[1]);
        acc[2] = fmaf(wA, f2, acc[2]); acc[3] = fmaf(wA, f3, acc[3]);
        acc[4] = fmaf(wA, f4, acc[4]); acc[5] = fmaf(wA, f5, acc[5]);
        acc[6] = fmaf(wA, f6, acc[6]); acc[7] = fmaf(wA, f7, acc[7]);
    }
    #pragma unroll
    for (int o = 16; o < 64; o <<= 1) {
        #pragma unroll
        for (int k = 0; k < 8; k++) acc[k] += __shfl_xor(acc[k], o);
        wsum += __shfl_xor(wsum, o);
    }

    if (lane < 16) {
        int ch0 = sub * 8;
        float invh = 1.f / (wsum + 1e-16f);
        float4 b0 = *(const float4*)(bias + ch0);
        float4 b1 = *(const float4*)(bias + ch0 + 4);
        union { __hip_bfloat16 h[8]; uint4 u; } o2;
        o2.h[0] = __float2bfloat16(fmaxf(fmaf(acc[0], invh, b0.x), 0.f));
        o2.h[1] = __float2bfloat16(fmaxf(fmaf(acc[1], invh, b0.y), 0.f));
        o2.h[2] = __float2bfloat16(fmaxf(fmaf(acc[2], invh, b0.z), 0.f));
        o2.h[3] = __float2bfloat16(fmaxf(fmaf(acc[3], invh, b0.w), 0.f));
        o2.h[4] = __float2bfloat16(fmaxf(fmaf(acc[4], invh, b1.x), 0.f));
        o2.h[5] = __float2bfloat16(fmaxf(fmaf(acc[5], invh, b1.y), 0.f));
        o2.h[6] = __float2bfloat16(fmaxf(fmaf(acc[6], invh, b1.z), 0.f));
        o2.h[7] = __float2bfloat16(fmaxf(fmaf(acc[7], invh, b1.w), 0.f));
        *(uint4*)(out + (size_t)d * 128 + ch0) = o2.u;
    }
}

// ---------------------------------------------------------------------------
// Edge softmax + aggregation, layer 2 (heads=1), RECORD-DRIVEN, + log_softmax.
// ---------------------------------------------------------------------------
__global__ __launch_bounds__(256) void edge_agg_l2(
    const int* __restrict__ offs, const uint2* __restrict__ rec2,
    const __hip_bfloat16* __restrict__ h2, const float* __restrict__ bias,
    float* __restrict__ out, int n) {
    int d = (blockIdx.x * blockDim.x + threadIdx.x) >> 6;
    int lane = threadIdx.x & 63;
    if (d >= n) return;
    int start = offs[d], end = offs[d + 1];
    int cnt = end - start;
    int sub = lane & 7;        // channel segment (8 ch)
    int g = lane >> 3;         // edge subgroup 0..7
    unsigned cboff = (unsigned)(sub * 8) * 2u;
    const char* hb = (const char*)h2;

    float wsum = 0.f;
    float acc[8];
    #pragma unroll
    for (int k = 0; k < 8; k++) acc[k] = 0.f;

    int full = cnt >> 3;
    int ib = start + g;
    int jj = 0;
    uint2 pA, pB, pC, pD;
    if (jj + 4 <= full) {
        pA = rec2[ib];       pB = rec2[ib + 8];
        pC = rec2[ib + 16];  pD = rec2[ib + 24];
    }
    for (; jj + 4 <= full; jj += 4) {
        uint2 rA = pA, rB = pB, rC = pC, rD = pD;
        if (jj + 8 <= full) {
            int nb = ib + (jj + 4) * 8;
            pA = rec2[nb];       pB = rec2[nb + 8];
            pC = rec2[nb + 16];  pD = rec2[nb + 24];
        }
        uint4 vA = *(const uint4*)(hb + (rA.x + cboff));
        uint4 vB = *(const uint4*)(hb + (rB.x + cboff));
        uint4 vC = *(const uint4*)(hb + (rC.x + cboff));
        uint4 vD = *(const uint4*)(hb + (rD.x + cboff));
        float wA = __uint_as_float(rA.y);
        float wB = __uint_as_float(rB.y);
        float wC = __uint_as_float(rC.y);
        float wD = __uint_as_float(rD.y);
        wsum += (wA + wB) + (wC + wD);
        float f0, f1, f2, f3, f4, f5, f6, f7;
        unpack2(vA.x, f0, f1); unpack2(vA.y, f2, f3);
        unpack2(vA.z, f4, f5); unpack2(vA.w, f6, f7);
        acc[0] = fmaf(wA, f0, acc[0]); acc[1] = fmaf(wA, f1, acc[1]);
        acc[2] = fmaf(wA, f2, acc[2]); acc[3] = fmaf(wA, f3, acc[3]);
        acc[4] = fmaf(wA, f4, acc[4]); acc[5] = fmaf(wA, f5, acc[5]);
        acc[6] = fmaf(wA, f6, acc[6]); acc[7] = fmaf(wA, f7, acc[7]);
        unpack2(vB.x, f0, f1); unpack2(vB.y, f2, f3);
        unpack2(vB.z, f4, f5); unpack2(vB.w, f6, f7);
        acc[0] = fmaf(wB, f0, acc[0]); acc[1] = fmaf(wB, f1, acc[1]);
        acc[2] = fmaf(wB, f2, acc[2]); acc[3] = fmaf(wB, f3, acc[3]);
        acc[4] = fmaf(wB, f4, acc[4]); acc[5] = fmaf(wB, f5, acc[5]);
        acc[6] = fmaf(wB, f6, acc[6]); acc[7] = fmaf(wB, f7, acc[7]);
        unpack2(vC.x, f0, f1); unpack2(vC.y, f2, f3);
        unpack2(vC.z, f4, f5); unpack2(vC.w, f6, f7);
        acc[0] = fmaf(wC, f0, acc[0]); acc[1] = fmaf(wC, f1, acc[1]);
        acc[2] = fmaf(wC, f2, acc[2]); acc[3] = fmaf(wC, f3, acc[3]);
        acc[4] = fmaf(wC, f4, acc[4]); acc[5] = fmaf(wC, f5, acc[5]);
        acc[6] = fmaf(wC, f6, acc[6]); acc[7] = fmaf(wC, f7, acc[7]);
        unpack2(vD.x, f0, f1); unpack2(vD.y, f2, f3);
        unpack2(vD.z, f4, f5); unpack2(vD.w, f6, f7);
        acc[0] = fmaf(wD, f0, acc[0]); acc[1] = fmaf(wD, f1, acc[1]);
        acc[2] = fmaf(wD, f2, acc[2]); acc[3] = fmaf(wD, f3, acc[3]);
        acc[4] = fmaf(wD, f4, acc[4]); acc[5] = fmaf(wD, f5, acc[5]);
        acc[6] = fmaf(wD, f6, acc[6]); acc[7] = fmaf(wD, f7, acc[7]);
    }
    for (; jj < full; jj++) {
        uint2 r = rec2[ib + jj * 8];
        uint4 v = *(const uint4*)(hb + (r.x + cboff));
        float wA = __uint_as_float(r.y);
        wsum += wA;
        float f0, f1, f2, f3, f4, f5, f6, f7;
        unpack2(v.x, f0, f1); unpack2(v.y, f2, f3);
        unpack2(v.z, f4, f5); unpack2(v.w, f6, f7);
        acc[0] = fmaf(wA, f0, acc[0]); acc[1] = fmaf(wA, f1, acc[1]);
        acc[2] = fmaf(wA, f2, acc[2]); acc[3] = fmaf(wA, f3, acc[3]);
        acc[4] = fmaf(wA, f4, acc[4]); acc[5] = fmaf(wA, f5, acc[5]);
        acc[6] = fmaf(wA, f6, acc[6]); acc[7] = fmaf(wA, f7, acc[7]);
    }
    if (full * 8 + g < cnt) {
        uint2 r = rec2[ib + full * 8];
        uint4 v = *(const uint4*)(hb + (r.x + cboff));
        float wA = __uint_as_float(r.y);
        wsum += wA;
        float f0, f1, f2, f3, f4, f5, f6, f7;
        unpack2(v.x, f0, f1); unpack2(v.y, f2, f3);
        unpack2(v.z, f4, f5); unpack2(v.w, f6, f7);
        acc[0] = fmaf(wA, f0, acc[0]); acc[1] = fmaf(wA, f1, acc[1]);
        acc[2] = fmaf(wA, f2, acc[2]); acc[3] = fmaf(wA, f3, acc[3]);
        acc[4] = fmaf(wA, f4, acc[4]); acc[5] = fmaf(wA, f5, acc[5]);
        acc[6] = fmaf(wA, f6, acc[6]); acc[7] = fmaf(wA, f7, acc[7]);
    }
    #pragma unroll
    for (int o = 8; o < 64; o <<= 1) {
        #pragma unroll
        for (int k = 0; k < 8; k++) acc[k] += __shfl_xor(acc[k], o);
        wsum += __shfl_xor(wsum, o);
    }

    int ch0 = sub * 8;
    float inv = 1.f / (wsum + 1e-16f);
    float4 b0 = *(const float4*)(bias + ch0);
    float4 b1 = *(const float4*)(bias + ch0 + 4);
    float v[8];
    v[0] = fmaf(acc[0], inv, b0.x); v[1] = fmaf(acc[1], inv, b0.y);
    v[2] = fmaf(acc[2], inv, b0.z); v[3] = fmaf(acc[3], inv, b0.w);
    v[4] = fmaf(acc[4], inv, b1.x); v[5] = fmaf(acc[5], inv, b1.y);
    v[6] = fmaf(acc[6], inv, b1.z); v[7] = fmaf(acc[7], inv, b1.w);

    float vm = v[0];
    #pragma unroll
    for (int k = 1; k < 8; k++) vm = fmaxf(vm, v[k]);
    #pragma unroll
    for (int o = 1; o < 8; o <<= 1) vm = fmaxf(vm, __shfl_xor(vm, o));
    float se_loc = 0.f;
    #pragma unroll
    for (int k = 0; k < 8; k++) se_loc += __expf(v[k] - vm);
    #pragma unroll
    for (int o = 1; o < 8; o <<= 1) se_loc += __shfl_xor(se_loc, o);
    float lse = vm + logf(se_loc);

    if (lane < 8) {
        float4 o0 = make_float4(v[0] - lse, v[1] - lse, v[2] - lse, v[3] - lse);
        float4 o1 = make_float4(v[4] - lse, v[5] - lse, v[6] - lse, v[7] - lse);
        *(float4*)(out + (size_t)d * 64 + ch0) = o0;
        *(float4*)(out + (size_t)d * 64 + ch0 + 4) = o1;
    }
}

// ---------------------------------------------------------------------------
// Launch.  Order: prep -> hist -> scan -> partition -> gemm1 ->
// bucket_csr(+rec1) -> agg1 -> gemm2 -> rec2 -> agg2.
// ---------------------------------------------------------------------------
extern "C" void kernel_launch(void* const* d_in, const int* in_sizes, int n_in,
                              void* d_out, int out_size, void* d_ws, size_t ws_size,
                              hipStream_t stream) {
    const float* x    = (const float*)d_in[0];
    const int*   ei   = (const int*)d_in[1];
    const float* W1   = (const float*)d_in[2];
    const float* as1w = (const float*)d_in[3];
    const float* ad1w = (const float*)d_in[4];
    const float* b1   = (const float*)d_in[5];
    const float* W2   = (const float*)d_in[6];
    const float* as2w = (const float*)d_in[7];
    const float* ad2w = (const float*)d_in[8];
    const float* b2   = (const float*)d_in[9];
    float* out = (float*)d_out;

    const int n = in_sizes[0] / 256;      // 50000
    const int E = in_sizes[1] / 2;        // 1600000
    const int tot = E + n;
    const int nbk = (n + BWIDTH - 1) / BWIDTH;

    char* p = (char*)d_ws;
    auto alloc = [&](size_t bytes) {
        void* r = (void*)p;
        p += (bytes + 255) & ~(size_t)255;
        return r;
    };
    int*   offs  = (int*)alloc((size_t)(n + 1) * 4);
    int*   tmp   = (int*)alloc((size_t)E * 4);
    int*   bcnt  = (int*)alloc(512 * 4);
    int*   bbase = (int*)alloc(512 * 4);
    int*   bcur  = (int*)alloc(512 * 4);
    uint4* rec1  = (uint4*)alloc((size_t)tot * 16);
    uint2* rec2  = (uint2*)alloc((size_t)tot * 8);
    __hip_bfloat16* W1t = (__hip_bfloat16*)alloc((size_t)128 * 256 * 2);
    __hip_bfloat16* W2t = (__hip_bfloat16*)alloc((size_t)64 * 128 * 2);
    __hip_bfloat16* h1  = (__hip_bfloat16*)alloc((size_t)n * 128 * 2);
    __hip_bfloat16* out1= (__hip_bfloat16*)alloc((size_t)n * 128 * 2);
    __hip_bfloat16* h2  = (__hip_bfloat16*)alloc((size_t)n * 64 * 2);
    float* a_s1 = (float*)alloc((size_t)n * 2 * 4);
    float* a_d1 = (float*)alloc((size_t)n * 2 * 4);
    float* a_s2 = (float*)alloc((size_t)n * 4);
    float* a_d2 = (float*)alloc((size_t)n * 4);

    int pblocks = (E + PCHUNK - 1) / PCHUNK;

    // --- prep (zero counters + weight transpose) ---
    prep_kernel<<<1 + (128 * 256 + 64 * 128 + 255) / 256, 256, 0, stream>>>(
        bcnt, W1, W2, W1t, W2t);

    // --- bucketed CSR build (pre-gemm part) ---
    bucket_hist<<<pblocks, 256, 0, stream>>>(ei, E, bcnt);
    bucket_scan<<<1, 512, 0, stream>>>(bcnt, bbase, bcur, nbk, n);
    partition_edges<<<pblocks, 256, 0, stream>>>(ei, E, bcur, tmp);

    // --- Layer 1 GEMM (needed by rec1 weights) ---
    gemm_att<false, 8, 2, 8><<<(n + 63) / 64, 256, 0, stream>>>(
        x, W1t, h1, as1w, ad1w, a_s1, a_d1, n);

    // --- CSR finalize + layer-1 edge records ---
    bucket_csr<<<nbk, 256, 0, stream>>>(bbase, tmp, offs, rec1, a_s1, a_d1, n, nbk);

    // --- Layer 1 aggregation ---
    edge_agg_l1<<<((size_t)n * 64 + 255) / 256, 256, 0, stream>>>(
        offs, rec1, h1, b1, out1, n);

    // --- Layer 2 ---
    gemm_att<true, 4, 1, 4><<<(n + 63) / 64, 256, 0, stream>>>(
        out1, W2t, h2, as2w, ad2w, a_s2, a_d2, n);
    build_rec2<<<(tot + 255) / 256, 256, 0, stream>>>(rec1, a_s2, a_d2, rec2, tot);
    edge_agg_l2<<<((size_t)n * 64 + 255) / 256, 256, 0, stream>>>(
        offs, rec2, h2, b2, out, n);
}

// Round 10
// 265.886 us; speedup vs baseline: 1.1049x; 1.1049x over previous
//
#include <hip/hip_runtime.h>
#include <hip/hip_bf16.h>
#include <math.h>

typedef short bf16x8 __attribute__((ext_vector_type(8)));
typedef float f32x4 __attribute__((ext_vector_type(4)));

#define BSHIFT 7
#define BWIDTH 128      // nodes per bucket
#define PCHUNK 4096     // edges per partition block

// ---------------------------------------------------------------------------
// prep: zero bucket counters (block 0) + bf16-transpose both weights
// ---------------------------------------------------------------------------
__global__ void prep_kernel(int* __restrict__ bcnt,
                            const float* __restrict__ W1, const float* __restrict__ W2,
                            __hip_bfloat16* __restrict__ W1t,
                            __hip_bfloat16* __restrict__ W2t) {
    if (blockIdx.x == 0) {
        bcnt[threadIdx.x] = 0;
        bcnt[threadIdx.x + 256] = 0;
        return;
    }
    int idx = (blockIdx.x - 1) * 256 + threadIdx.x;
    const int n1 = 128 * 256;
    if (idx < n1) {
        int nn = idx >> 8, kk = idx & 255;
        W1t[idx] = __float2bfloat16(W1[kk * 128 + nn]);
    } else {
        int j = idx - n1;
        if (j < 64 * 128) {
            int nn = j >> 7, kk = j & 127;
            W2t[j] = __float2bfloat16(W2[kk * 64 + nn]);
        }
    }
}

// ---------------------------------------------------------------------------
// Bucketed CSR build; tmp packed: (src << 7) | dst_local
// ---------------------------------------------------------------------------
__global__ __launch_bounds__(256) void bucket_hist(const int* __restrict__ ei, int E,
                                                   int* __restrict__ bcnt) {
    __shared__ int h[512];
    int tid = threadIdx.x;
    for (int i = tid; i < 512; i += 256) h[i] = 0;
    __syncthreads();
    int start = blockIdx.x * PCHUNK;
    int cnt = min(PCHUNK, E - start);
    for (int i = tid; i < cnt; i += 256)
        atomicAdd(&h[ei[E + start + i] >> BSHIFT], 1);
    __syncthreads();
    for (int i = tid; i < 512; i += 256)
        if (h[i]) atomicAdd(&bcnt[i], h[i]);
}

__global__ __launch_bounds__(512) void bucket_scan(const int* __restrict__ bcnt,
                                                   int* __restrict__ bbase,
                                                   int* __restrict__ bcur,
                                                   int nbk, int n) {
    __shared__ int s[512];
    int tid = threadIdx.x;
    int nodes = 0;
    if (tid < nbk) nodes = min(BWIDTH, n - (tid << BSHIFT));
    int v = (tid < nbk) ? bcnt[tid] + nodes : 0;
    s[tid] = v;
    __syncthreads();
    #pragma unroll
    for (int o = 1; o < 512; o <<= 1) {
        int t = (tid >= o) ? s[tid - o] : 0;
        __syncthreads();
        s[tid] += t;
        __syncthreads();
    }
    if (tid < nbk) {
        int ex = s[tid] - v;
        bbase[tid] = ex;
        bcur[tid] = ex - (tid << BSHIFT);
    }
    if (tid == nbk) bbase[nbk] = s[tid];
}

__global__ __launch_bounds__(256) void partition_edges(const int* __restrict__ ei, int E,
                                                       int* __restrict__ bcur,
                                                       int* __restrict__ tmp) {
    __shared__ int2 stage[PCHUNK];
    __shared__ int h[512];
    __shared__ int lbase[512];
    int tid = threadIdx.x;
    int start = blockIdx.x * PCHUNK;
    int cnt = min(PCHUNK, E - start);
    for (int i = tid; i < 512; i += 256) h[i] = 0;
    __syncthreads();
    for (int i = tid; i < cnt; i += 256) {
        int s = ei[start + i];
        int d = ei[E + start + i];
        stage[i] = make_int2(s, d);
        atomicAdd(&h[d >> BSHIFT], 1);
    }
    __syncthreads();
    for (int i = tid; i < 512; i += 256) {
        if (h[i] > 0) lbase[i] = atomicAdd(&bcur[i], h[i]);
        h[i] = 0;
    }
    __syncthreads();
    for (int i = tid; i < cnt; i += 256) {
        int2 e = stage[i];
        int b = e.y >> BSHIFT;
        int r = atomicAdd(&h[b], 1);
        tmp[lbase[b] + r] = (e.x << BSHIFT) | (e.y & (BWIDTH - 1));
    }
}

__global__ __launch_bounds__(256) void bucket_csr(const int* __restrict__ bbase,
                                                  const int* __restrict__ tmp,
                                                  int* __restrict__ offs,
                                                  int* __restrict__ srcs,
                                                  int n, int nbk) {
    __shared__ int cnt[BWIDTH];
    __shared__ int sa[BWIDTH];
    __shared__ int cur[BWIDTH];
    int b = blockIdx.x;
    int tid = threadIdx.x;
    int node0 = b << BSHIFT;
    int nnodes = min(BWIDTH, n - node0);
    int cb = bbase[b];
    int ce = bbase[b + 1];
    int tb = cb - node0;
    int ecnt = (ce - cb) - nnodes;

    if (tid < BWIDTH) cnt[tid] = (tid < nnodes) ? 1 : 0;
    __syncthreads();
    for (int i = tid; i < ecnt; i += 256)
        atomicAdd(&cnt[tmp[tb + i] & (BWIDTH - 1)], 1);
    __syncthreads();
    if (tid < BWIDTH) sa[tid] = cnt[tid];
    __syncthreads();
    #pragma unroll
    for (int o = 1; o < BWIDTH; o <<= 1) {
        int v = 0;
        if (tid < BWIDTH) { v = sa[tid]; if (tid >= o) v += sa[tid - o]; }
        __syncthreads();
        if (tid < BWIDTH) sa[tid] = v;
        __syncthreads();
    }
    if (tid < BWIDTH) {
        int ex = sa[tid] - cnt[tid];
        if (tid < nnodes) {
            offs[node0 + tid] = cb + ex;
            srcs[cb + ex] = node0 + tid;
        }
        cur[tid] = ex + (tid < nnodes ? 1 : 0);
    }
    if (b == nbk - 1 && tid == 0) offs[n] = ce;
    __syncthreads();
    for (int i = tid; i < ecnt; i += 256) {
        int e = tmp[tb + i];
        int li = e & (BWIDTH - 1);
        int r = atomicAdd(&cur[li], 1);
        srcs[cb + r] = e >> BSHIFT;
    }
}

// ---------------------------------------------------------------------------
// MFMA bf16 GEMM + fused attention dots. B-panel staged in LDS (the REUSED
// operand) in 128-k-column chunks; row pad +8 elems. A streamed per-lane from
// global, chunk loads issued BEFORE the B-stage barrier.
// ---------------------------------------------------------------------------
template <bool A_BF16, int NT, int HEADS, int KSTEPS>
__global__ __launch_bounds__(256) void gemm_att(
    const void* __restrict__ Av, const __hip_bfloat16* __restrict__ Bt,
    __hip_bfloat16* __restrict__ C,
    const float* __restrict__ atts, const float* __restrict__ attd,
    float* __restrict__ a_s, float* __restrict__ a_d, int M) {
    constexpr int K = KSTEPS * 32;
    constexpr int N = NT * 16;
    constexpr int KH = 128;
    constexpr int NCH = (K + KH - 1) / KH;
    constexpr int LDB = KH + 8;
    __shared__ __hip_bfloat16 Bs[N][LDB];

    int tid = threadIdx.x;
    int w = tid >> 6, l = tid & 63;
    int q = l >> 4, m16 = l & 15;
    int bm = blockIdx.x * 64;
    int arow = bm + w * 16 + m16;
    if (arow >= M) arow = M - 1;

    f32x4 acc[NT];
    #pragma unroll
    for (int t = 0; t < NT; t++) acc[t] = (f32x4){0.f, 0.f, 0.f, 0.f};

    #pragma unroll
    for (int ch = 0; ch < NCH; ch++) {
        const int cb = ch * KH;
        bf16x8 af[4];
        float4 st[8];
        if (A_BF16) {
            const __hip_bfloat16* A = (const __hip_bfloat16*)Av + (size_t)arow * K + cb + q * 8;
            #pragma unroll
            for (int t = 0; t < 4; t++)
                af[t] = *(const bf16x8*)(A + t * 32);
        } else {
            const float* A = (const float*)Av + (size_t)arow * K + cb + q * 8;
            #pragma unroll
            for (int t = 0; t < 4; t++) {
                st[2 * t]     = *(const float4*)(A + t * 32);
                st[2 * t + 1] = *(const float4*)(A + t * 32 + 4);
            }
        }
        for (int i = tid; i < (N * KH) / 8; i += 256) {
            int row = i >> 4;
            int k = (i & 15) * 8;
            *(uint4*)&Bs[row][k] = *(const uint4*)(Bt + (size_t)row * K + cb + k);
        }
        __syncthreads();
        if (!A_BF16) {
            #pragma unroll
            for (int t = 0; t < 4; t++) {
                union { __hip_bfloat16 h[8]; bf16x8 v; } u;
                float4 v0 = st[2 * t], v1 = st[2 * t + 1];
                u.h[0] = __float2bfloat16(v0.x); u.h[1] = __float2bfloat16(v0.y);
                u.h[2] = __float2bfloat16(v0.z); u.h[3] = __float2bfloat16(v0.w);
                u.h[4] = __float2bfloat16(v1.x); u.h[5] = __float2bfloat16(v1.y);
                u.h[6] = __float2bfloat16(v1.z); u.h[7] = __float2bfloat16(v1.w);
                af[t] = u.v;
            }
        }
        #pragma unroll
        for (int t = 0; t < 4; t++) {
            #pragma unroll
            for (int c = 0; c < NT; c++) {
                bf16x8 b = *(const bf16x8*)&Bs[c * 16 + m16][t * 32 + q * 8];
                acc[c] = __builtin_amdgcn_mfma_f32_16x16x32_bf16(af[t], b, acc[c], 0, 0, 0);
            }
        }
        if (ch + 1 < NCH) __syncthreads();
    }

    #pragma unroll
    for (int t = 0; t < NT; t++) {
        #pragma unroll
        for (int r = 0; r < 4; r++) {
            int row = bm + w * 16 + q * 4 + r;
            if (row < M) C[(size_t)row * N + t * 16 + m16] = __float2bfloat16(acc[t][r]);
        }
    }

    float ps[HEADS][4], pd[HEADS][4];
    #pragma unroll
    for (int hh = 0; hh < HEADS; hh++)
        #pragma unroll
        for (int r = 0; r < 4; r++) { ps[hh][r] = 0.f; pd[hh][r] = 0.f; }
    #pragma unroll
    for (int t = 0; t < NT; t++) {
        int ch = t * 16 + m16;
        float asw = atts[ch], adw = attd[ch];
        int hh = (HEADS == 2) ? (t >> 2) : 0;
        #pragma unroll
        for (int r = 0; r < 4; r++) {
            ps[hh][r] = fmaf(acc[t][r], asw, ps[hh][r]);
            pd[hh][r] = fmaf(acc[t][r], adw, pd[hh][r]);
        }
    }
    #pragma unroll
    for (int o = 1; o < 16; o <<= 1) {
        #pragma unroll
        for (int hh = 0; hh < HEADS; hh++)
            #pragma unroll
            for (int r = 0; r < 4; r++) {
                ps[hh][r] += __shfl_xor(ps[hh][r], o);
                pd[hh][r] += __shfl_xor(pd[hh][r], o);
            }
    }
    if (m16 == 0) {
        #pragma unroll
        for (int r = 0; r < 4; r++) {
            int row = bm + w * 16 + q * 4 + r;
            if (row < M) {
                if (HEADS == 2) {
                    a_s[row * 2]     = ps[0][r];
                    a_s[row * 2 + 1] = ps[1][r];
                    a_d[row * 2]     = pd[0][r];
                    a_d[row * 2 + 1] = pd[1][r];
                } else {
                    a_s[row] = ps[0][r];
                    a_d[row] = pd[0][r];
                }
            }
        }
    }
}

__device__ __forceinline__ float leaky(float r) {
    return r < 0.f ? 0.2f * r : r;
}

__device__ __forceinline__ void unpack2(unsigned u, float& lo, float& hi) {
    lo = __uint_as_float(u << 16);
    hi = __uint_as_float(u & 0xffff0000u);
}

// ---------------------------------------------------------------------------
// Edge softmax + aggregation, layer 1 (heads=2). SHUFFLE-FREE: each 16-lane
// channel-group loads its edge's src index and attention coeff DIRECTLY
// (uniform addr per group -> broadcast), recomputes exp redundantly (VALU has
// headroom). Src-index loads pipelined one unroll-4 iteration ahead.
// Denominator = per-lane weight sum reduced over edge-group lane bits.
// ---------------------------------------------------------------------------
__global__ __launch_bounds__(256) void edge_agg_l1(
    const int* __restrict__ offs, const int* __restrict__ srcs,
    const __hip_bfloat16* __restrict__ h1, const float* __restrict__ asv,
    const float* __restrict__ adv, const float* __restrict__ bias,
    __hip_bfloat16* __restrict__ out, int n) {
    int d = (blockIdx.x * blockDim.x + threadIdx.x) >> 6;
    int lane = threadIdx.x & 63;
    if (d >= n) return;
    int start = offs[d], end = offs[d + 1];
    int cnt = end - start;
    int sub = lane & 15;        // channel segment (8 ch)
    int g = lane >> 4;          // edge subgroup 0..3
    int ch0 = sub * 8;
    int hsel = sub >> 3;        // head of this lane's channels
    float ad = adv[2 * d + hsel];

    float wsum = 0.f;
    float acc[8];
    #pragma unroll
    for (int k = 0; k < 8; k++) acc[k] = 0.f;

    int full = cnt >> 2;        // fully-populated 4-edge steps
    int ib = start + g;         // this lane's edge index for step 0
    int jj = 0;
    int pA = 0, pB = 0, pC = 0, pD = 0;
    if (jj + 4 <= full) {
        pA = srcs[ib];      pB = srcs[ib + 4];
        pC = srcs[ib + 8];  pD = srcs[ib + 12];
    }
    for (; jj + 4 <= full; jj += 4) {
        int sA = pA, sB = pB, sC = pC, sD = pD;
        if (jj + 8 <= full) {
            int nb = ib + (jj + 4) * 4;
            pA = srcs[nb];      pB = srcs[nb + 4];
            pC = srcs[nb + 8];  pD = srcs[nb + 12];
        }
        uint4 vA = *(const uint4*)(h1 + (size_t)sA * 128 + ch0);
        uint4 vB = *(const uint4*)(h1 + (size_t)sB * 128 + ch0);
        uint4 vC = *(const uint4*)(h1 + (size_t)sC * 128 + ch0);
        uint4 vD = *(const uint4*)(h1 + (size_t)sD * 128 + ch0);
        float aA = asv[2 * sA + hsel];
        float aB = asv[2 * sB + hsel];
        float aC = asv[2 * sC + hsel];
        float aD = asv[2 * sD + hsel];
        float wA = __expf(leaky(aA + ad));
        float wB = __expf(leaky(aB + ad));
        float wC = __expf(leaky(aC + ad));
        float wD = __expf(leaky(aD + ad));
        wsum += (wA + wB) + (wC + wD);
        float f0, f1, f2, f3, f4, f5, f6, f7;
        unpack2(vA.x, f0, f1); unpack2(vA.y, f2, f3);
        unpack2(vA.z, f4, f5); unpack2(vA.w, f6, f7);
        acc[0] = fmaf(wA, f0, acc[0]); acc[1] = fmaf(wA, f1, acc[1]);
        acc[2] = fmaf(wA, f2, acc[2]); acc[3] = fmaf(wA, f3, acc[3]);
        acc[4] = fmaf(wA, f4, acc[4]); acc[5] = fmaf(wA, f5, acc[5]);
        acc[6] = fmaf(wA, f6, acc[6]); acc[7] = fmaf(wA, f7, acc[7]);
        unpack2(vB.x, f0, f1); unpack2(vB.y, f2, f3);
        unpack2(vB.z, f4, f5); unpack2(vB.w, f6, f7);
        acc[0] = fmaf(wB, f0, acc[0]); acc[1] = fmaf(wB, f1, acc[1]);
        acc[2] = fmaf(wB, f2, acc[2]); acc[3] = fmaf(wB, f3, acc[3]);
        acc[4] = fmaf(wB, f4, acc[4]); acc[5] = fmaf(wB, f5, acc[5]);
        acc[6] = fmaf(wB, f6, acc[6]); acc[7] = fmaf(wB, f7, acc[7]);
        unpack2(vC.x, f0, f1); unpack2(vC.y, f2, f3);
        unpack2(vC.z, f4, f5); unpack2(vC.w, f6, f7);
        acc[0] = fmaf(wC, f0, acc[0]); acc[1] = fmaf(wC, f1, acc[1]);
        acc[2] = fmaf(wC, f2, acc[2]); acc[3] = fmaf(wC, f3, acc[3]);
        acc[4] = fmaf(wC, f4, acc[4]); acc[5] = fmaf(wC, f5, acc[5]);
        acc[6] = fmaf(wC, f6, acc[6]); acc[7] = fmaf(wC, f7, acc[7]);
        unpack2(vD.x, f0, f1); unpack2(vD.y, f2, f3);
        unpack2(vD.z, f4, f5); unpack2(vD.w, f6, f7);
        acc[0] = fmaf(wD, f0, acc[0]); acc[1] = fmaf(wD, f1, acc[1]);
        acc[2] = fmaf(wD, f2, acc[2]); acc[3] = fmaf(wD, f3, acc[3]);
        acc[4] = fmaf(wD, f4, acc[4]); acc[5] = fmaf(wD, f5, acc[5]);
        acc[6] = fmaf(wD, f6, acc[6]); acc[7] = fmaf(wD, f7, acc[7]);
    }
    for (; jj < full; jj++) {
        int s = srcs[ib + jj * 4];
        uint4 v = *(const uint4*)(h1 + (size_t)s * 128 + ch0);
        float a = asv[2 * s + hsel];
        float wA = __expf(leaky(a + ad));
        wsum += wA;
        float f0, f1, f2, f3, f4, f5, f6, f7;
        unpack2(v.x, f0, f1); unpack2(v.y, f2, f3);
        unpack2(v.z, f4, f5); unpack2(v.w, f6, f7);
        acc[0] = fmaf(wA, f0, acc[0]); acc[1] = fmaf(wA, f1, acc[1]);
        acc[2] = fmaf(wA, f2, acc[2]); acc[3] = fmaf(wA, f3, acc[3]);
        acc[4] = fmaf(wA, f4, acc[4]); acc[5] = fmaf(wA, f5, acc[5]);
        acc[6] = fmaf(wA, f6, acc[6]); acc[7] = fmaf(wA, f7, acc[7]);
    }
    if (full * 4 + g < cnt) {   // tail edges (<4)
        int s = srcs[ib + full * 4];
        uint4 v = *(const uint4*)(h1 + (size_t)s * 128 + ch0);
        float a = asv[2 * s + hsel];
        float wA = __expf(leaky(a + ad));
        wsum += wA;
        float f0, f1, f2, f3, f4, f5, f6, f7;
        unpack2(v.x, f0, f1); unpack2(v.y, f2, f3);
        unpack2(v.z, f4, f5); unpack2(v.w, f6, f7);
        acc[0] = fmaf(wA, f0, acc[0]); acc[1] = fmaf(wA, f1, acc[1]);
        acc[2] = fmaf(wA, f2, acc[2]); acc[3] = fmaf(wA, f3, acc[3]);
        acc[4] = fmaf(wA, f4, acc[4]); acc[5] = fmaf(wA, f5, acc[5]);
        acc[6] = fmaf(wA, f6, acc[6]); acc[7] = fmaf(wA, f7, acc[7]);
    }
    // fold the 4 edge subgroups (lane bits 4,5); also completes denominator
    #pragma unroll
    for (int o = 16; o < 64; o <<= 1) {
        #pragma unroll
        for (int k = 0; k < 8; k++) acc[k] += __shfl_xor(acc[k], o);
        wsum += __shfl_xor(wsum, o);
    }

    if (lane < 16) {
        float inv = 1.f / (wsum + 1e-16f);
        float4 b0 = *(const float4*)(bias + ch0);
        float4 b1 = *(const float4*)(bias + ch0 + 4);
        union { __hip_bfloat16 h[8]; uint4 u; } o2;
        o2.h[0] = __float2bfloat16(fmaxf(fmaf(acc[0], inv, b0.x), 0.f));
        o2.h[1] = __float2bfloat16(fmaxf(fmaf(acc[1], inv, b0.y), 0.f));
        o2.h[2] = __float2bfloat16(fmaxf(fmaf(acc[2], inv, b0.z), 0.f));
        o2.h[3] = __float2bfloat16(fmaxf(fmaf(acc[3], inv, b0.w), 0.f));
        o2.h[4] = __float2bfloat16(fmaxf(fmaf(acc[4], inv, b1.x), 0.f));
        o2.h[5] = __float2bfloat16(fmaxf(fmaf(acc[5], inv, b1.y), 0.f));
        o2.h[6] = __float2bfloat16(fmaxf(fmaf(acc[6], inv, b1.z), 0.f));
        o2.h[7] = __float2bfloat16(fmaxf(fmaf(acc[7], inv, b1.w), 0.f));
        *(uint4*)(out + (size_t)d * 128 + ch0) = o2.u;
    }
}

// ---------------------------------------------------------------------------
// Edge softmax + aggregation, layer 2 (heads=1), shuffle-free, + log_softmax.
// 8-lane channel-groups, 8 edges/step.
// ---------------------------------------------------------------------------
__global__ __launch_bounds__(256) void edge_agg_l2(
    const int* __restrict__ offs, const int* __restrict__ srcs,
    const __hip_bfloat16* __restrict__ h2, const float* __restrict__ asv,
    const float* __restrict__ adv, const float* __restrict__ bias,
    float* __restrict__ out, int n) {
    int d = (blockIdx.x * blockDim.x + threadIdx.x) >> 6;
    int lane = threadIdx.x & 63;
    if (d >= n) return;
    int start = offs[d], end = offs[d + 1];
    int cnt = end - start;
    int sub = lane & 7;        // channel segment (8 ch)
    int g = lane >> 3;         // edge subgroup 0..7
    int ch0 = sub * 8;
    float ad = adv[d];

    float wsum = 0.f;
    float acc[8];
    #pragma unroll
    for (int k = 0; k < 8; k++) acc[k] = 0.f;

    int full = cnt >> 3;       // fully-populated 8-edge steps
    int ib = start + g;
    int jj = 0;
    int pA = 0, pB = 0, pC = 0, pD = 0;
    if (jj + 4 <= full) {
        pA = srcs[ib];       pB = srcs[ib + 8];
        pC = srcs[ib + 16];  pD = srcs[ib + 24];
    }
    for (; jj + 4 <= full; jj += 4) {
        int sA = pA, sB = pB, sC = pC, sD = pD;
        if (jj + 8 <= full) {
            int nb = ib + (jj + 4) * 8;
            pA = srcs[nb];       pB = srcs[nb + 8];
            pC = srcs[nb + 16];  pD = srcs[nb + 24];
        }
        uint4 vA = *(const uint4*)(h2 + (size_t)sA * 64 + ch0);
        uint4 vB = *(const uint4*)(h2 + (size_t)sB * 64 + ch0);
        uint4 vC = *(const uint4*)(h2 + (size_t)sC * 64 + ch0);
        uint4 vD = *(const uint4*)(h2 + (size_t)sD * 64 + ch0);
        float aA = asv[sA], aB = asv[sB], aC = asv[sC], aD = asv[sD];
        float wA = __expf(leaky(aA + ad));
        float wB = __expf(leaky(aB + ad));
        float wC = __expf(leaky(aC + ad));
        float wD = __expf(leaky(aD + ad));
        wsum += (wA + wB) + (wC + wD);
        float f0, f1, f2, f3, f4, f5, f6, f7;
        unpack2(vA.x, f0, f1); unpack2(vA.y, f2, f3);
        unpack2(vA.z, f4, f5); unpack2(vA.w, f6, f7);
        acc[0] = fmaf(wA, f0, acc[0]); acc[1] = fmaf(wA, f1, acc[1]);
        acc[2] = fmaf(wA, f2, acc[2]); acc[3] = fmaf(wA, f3, acc[3]);
        acc[4] = fmaf(wA, f4, acc[4]); acc[5] = fmaf(wA, f5, acc[5]);
        acc[6] = fmaf(wA, f6, acc[6]); acc[7] = fmaf(wA, f7, acc[7]);
        unpack2(vB.x, f0, f1); unpack2(vB.y, f2, f3);
        unpack2(vB.z, f4, f5); unpack2(vB.w, f6, f7);
        acc[0] = fmaf(wB, f0, acc[0]); acc[1] = fmaf(wB, f1, acc[1]);
        acc[2] = fmaf(wB, f2, acc[2]); acc[3] = fmaf(wB, f3, acc[3]);
        acc[4] = fmaf(wB, f4, acc[4]); acc[5] = fmaf(wB, f5, acc[5]);
        acc[6] = fmaf(wB, f6, acc[6]); acc[7] = fmaf(wB, f7, acc[7]);
        unpack2(vC.x, f0, f1); unpack2(vC.y, f2, f3);
        unpack2(vC.z, f4, f5); unpack2(vC.w, f6, f7);
        acc[0] = fmaf(wC, f0, acc[0]); acc[1] = fmaf(wC, f1, acc[1]);
        acc[2] = fmaf(wC, f2, acc[2]); acc[3] = fmaf(wC, f3, acc[3]);
        acc[4] = fmaf(wC, f4, acc[4]); acc[5] = fmaf(wC, f5, acc[5]);
        acc[6] = fmaf(wC, f6, acc[6]); acc[7] = fmaf(wC, f7, acc[7]);
        unpack2(vD.x, f0, f1); unpack2(vD.y, f2, f3);
        unpack2(vD.z, f4, f5); unpack2(vD.w, f6, f7);
        acc[0] = fmaf(wD, f0, acc[0]); acc[1] = fmaf(wD, f1, acc[1]);
        acc[2] = fmaf(wD, f2, acc[2]); acc[3] = fmaf(wD, f3, acc[3]);
        acc[4] = fmaf(wD, f4, acc[4]); acc[5] = fmaf(wD, f5, acc[5]);
        acc[6] = fmaf(wD, f6, acc[6]); acc[7] = fmaf(wD, f7, acc[7]);
    }
    for (; jj < full; jj++) {
        int s = srcs[ib + jj * 8];
        uint4 v = *(const uint4*)(h2 + (size_t)s * 64 + ch0);
        float a = asv[s];
        float wA = __expf(leaky(a + ad));
        wsum += wA;
        float f0, f1, f2, f3, f4, f5, f6, f7;
        unpack2(v.x, f0, f1); unpack2(v.y, f2, f3);
        unpack2(v.z, f4, f5); unpack2(v.w, f6, f7);
        acc[0] = fmaf(wA, f0, acc[0]); acc[1] = fmaf(wA, f1, acc[1]);
        acc[2] = fmaf(wA, f2, acc[2]); acc[3] = fmaf(wA, f3, acc[3]);
        acc[4] = fmaf(wA, f4, acc[4]); acc[5] = fmaf(wA, f5, acc[5]);
        acc[6] = fmaf(wA, f6, acc[6]); acc[7] = fmaf(wA, f7, acc[7]);
    }
    if (full * 8 + g < cnt) {  // tail edges (<8)
        int s = srcs[ib + full * 8];
        uint4 v = *(const uint4*)(h2 + (size_t)s * 64 + ch0);
        float a = asv[s];
        float wA = __expf(leaky(a + ad));
        wsum += wA;
        float f0, f1, f2, f3, f4, f5, f6, f7;
        unpack2(v.x, f0, f1); unpack2(v.y, f2, f3);
        unpack2(v.z, f4, f5); unpack2(v.w, f6, f7);
        acc[0] = fmaf(wA, f0, acc[0]); acc[1] = fmaf(wA, f1, acc[1]);
        acc[2] = fmaf(wA, f2, acc[2]); acc[3] = fmaf(wA, f3, acc[3]);
        acc[4] = fmaf(wA, f4, acc[4]); acc[5] = fmaf(wA, f5, acc[5]);
        acc[6] = fmaf(wA, f6, acc[6]); acc[7] = fmaf(wA, f7, acc[7]);
    }
    #pragma unroll
    for (int o = 8; o < 64; o <<= 1) {
        #pragma unroll
        for (int k = 0; k < 8; k++) acc[k] += __shfl_xor(acc[k], o);
        wsum += __shfl_xor(wsum, o);
    }

    float inv = 1.f / (wsum + 1e-16f);
    float4 b0 = *(const float4*)(bias + ch0);
    float4 b1 = *(const float4*)(bias + ch0 + 4);
    float v[8];
    v[0] = fmaf(acc[0], inv, b0.x); v[1] = fmaf(acc[1], inv, b0.y);
    v[2] = fmaf(acc[2], inv, b0.z); v[3] = fmaf(acc[3], inv, b0.w);
    v[4] = fmaf(acc[4], inv, b1.x); v[5] = fmaf(acc[5], inv, b1.y);
    v[6] = fmaf(acc[6], inv, b1.z); v[7] = fmaf(acc[7], inv, b1.w);

    float vm = v[0];
    #pragma unroll
    for (int k = 1; k < 8; k++) vm = fmaxf(vm, v[k]);
    #pragma unroll
    for (int o = 1; o < 8; o <<= 1) vm = fmaxf(vm, __shfl_xor(vm, o));
    float se_loc = 0.f;
    #pragma unroll
    for (int k = 0; k < 8; k++) se_loc += __expf(v[k] - vm);
    #pragma unroll
    for (int o = 1; o < 8; o <<= 1) se_loc += __shfl_xor(se_loc, o);
    float lse = vm + logf(se_loc);

    if (lane < 8) {
        float4 o0 = make_float4(v[0] - lse, v[1] - lse, v[2] - lse, v[3] - lse);
        float4 o1 = make_float4(v[4] - lse, v[5] - lse, v[6] - lse, v[7] - lse);
        *(float4*)(out + (size_t)d * 64 + ch0) = o0;
        *(float4*)(out + (size_t)d * 64 + ch0 + 4) = o1;
    }
}

// ---------------------------------------------------------------------------
// Launch
// ---------------------------------------------------------------------------
extern "C" void kernel_launch(void* const* d_in, const int* in_sizes, int n_in,
                              void* d_out, int out_size, void* d_ws, size_t ws_size,
                              hipStream_t stream) {
    const float* x    = (const float*)d_in[0];
    const int*   ei   = (const int*)d_in[1];
    const float* W1   = (const float*)d_in[2];
    const float* as1w = (const float*)d_in[3];
    const float* ad1w = (const float*)d_in[4];
    const float* b1   = (const float*)d_in[5];
    const float* W2   = (const float*)d_in[6];
    const float* as2w = (const float*)d_in[7];
    const float* ad2w = (const float*)d_in[8];
    const float* b2   = (const float*)d_in[9];
    float* out = (float*)d_out;

    const int n = in_sizes[0] / 256;      // 50000
    const int E = in_sizes[1] / 2;        // 1600000
    const int tot = E + n;
    const int nbk = (n + BWIDTH - 1) / BWIDTH;

    char* p = (char*)d_ws;
    auto alloc = [&](size_t bytes) {
        void* r = (void*)p;
        p += (bytes + 255) & ~(size_t)255;
        return r;
    };
    int*   offs  = (int*)alloc((size_t)(n + 1) * 4);
    int*   srcs  = (int*)alloc((size_t)tot * 4);
    int*   tmp   = (int*)alloc((size_t)E * 4);
    int*   bcnt  = (int*)alloc(512 * 4);
    int*   bbase = (int*)alloc(512 * 4);
    int*   bcur  = (int*)alloc(512 * 4);
    __hip_bfloat16* W1t = (__hip_bfloat16*)alloc((size_t)128 * 256 * 2);
    __hip_bfloat16* W2t = (__hip_bfloat16*)alloc((size_t)64 * 128 * 2);
    __hip_bfloat16* h1  = (__hip_bfloat16*)alloc((size_t)n * 128 * 2);
    __hip_bfloat16* out1= (__hip_bfloat16*)alloc((size_t)n * 128 * 2);
    __hip_bfloat16* h2  = (__hip_bfloat16*)alloc((size_t)n * 64 * 2);
    float* a_s1 = (float*)alloc((size_t)n * 2 * 4);
    float* a_d1 = (float*)alloc((size_t)n * 2 * 4);
    float* a_s2 = (float*)alloc((size_t)n * 4);
    float* a_d2 = (float*)alloc((size_t)n * 4);

    int pblocks = (E + PCHUNK - 1) / PCHUNK;

    // --- prep (zero counters + weight transpose) ---
    prep_kernel<<<1 + (128 * 256 + 64 * 128 + 255) / 256, 256, 0, stream>>>(
        bcnt, W1, W2, W1t, W2t);

    // --- bucketed CSR build ---
    bucket_hist<<<pblocks, 256, 0, stream>>>(ei, E, bcnt);
    bucket_scan<<<1, 512, 0, stream>>>(bcnt, bbase, bcur, nbk, n);
    partition_edges<<<pblocks, 256, 0, stream>>>(ei, E, bcur, tmp);
    bucket_csr<<<nbk, 256, 0, stream>>>(bbase, tmp, offs, srcs, n, nbk);

    // --- Layer 1 ---
    gemm_att<false, 8, 2, 8><<<(n + 63) / 64, 256, 0, stream>>>(
        x, W1t, h1, as1w, ad1w, a_s1, a_d1, n);
    edge_agg_l1<<<((size_t)n * 64 + 255) / 256, 256, 0, stream>>>(
        offs, srcs, h1, a_s1, a_d1, b1, out1, n);

    // --- Layer 2 ---
    gemm_att<true, 4, 1, 4><<<(n + 63) / 64, 256, 0, stream>>>(
        out1, W2t, h2, as2w, ad2w, a_s2, a_d2, n);
    edge_agg_l2<<<((size_t)n * 64 + 255) / 256, 256, 0, stream>>>(
        offs, srcs, h2, a_s2, a_d2, b2, out, n);
}